// Round 1
// baseline (8825.498 us; speedup 1.0000x reference)
//
#include <hip/hip_runtime.h>

// ---------------------------------------------------------------------------
// SQLDecoder: 48-step recurrent decoder with dot-product attention.
// Key restructurings vs reference:
//   * scores = src @ (h @ W_att)  -- never materialize src_lin [B,S,H]
//   * single-pass online-softmax attention (K == V == src), src cached as bf16
//   * all recurrent GEMMs in bf16 MFMA (16x16x32), fp32 accum + fp32 cell/readout
// B=256 S=512 E=H=AV=1024 A=TY=128 T=48 NP=97 NT=20 IN=1280 KCAT=2304
// ---------------------------------------------------------------------------

typedef short s16x8 __attribute__((ext_vector_type(8)));
typedef float f32x4 __attribute__((ext_vector_type(4)));

__device__ __forceinline__ unsigned short f2b(float x) {
  unsigned int u = __float_as_uint(x);
  return (unsigned short)((u + 0x7fffu + ((u >> 16) & 1u)) >> 16);  // RNE
}
__device__ __forceinline__ float b2f(unsigned short h) {
  return __uint_as_float(((unsigned int)h) << 16);
}
__device__ __forceinline__ float sigm(float x) { return 1.f / (1.f + __expf(-x)); }

// ---------------- prep kernels (run every call; deterministic) --------------

// max-pool over s + bf16 conversion of src. grid = B*4, block = 256 (e-strip)
template <int WRITE_B16>
__global__ __launch_bounds__(256) void pool_convert(const float* __restrict__ src,
                                                    unsigned short* __restrict__ srcb,
                                                    float* __restrict__ pooled) {
  int b = blockIdx.x >> 2;
  int e = (blockIdx.x & 3) * 256 + threadIdx.x;
  const float* p = src + (size_t)b * 524288 + e;
  float m = -3e38f;
  for (int s = 0; s < 512; ++s) {
    float v = p[(size_t)s * 1024];
    m = fmaxf(m, v);
    if (WRITE_B16) srcb[(size_t)b * 524288 + (size_t)s * 1024 + e] = f2b(v);
  }
  pooled[b * 1024 + e] = m;
}

// Wcat[n][0:1280)=W_ih[n], [1280:2304)=W_hh[n]  (bf16, K-contiguous)
__global__ __launch_bounds__(256) void conv_wcat(const float* __restrict__ wih,
                                                 const float* __restrict__ whh,
                                                 unsigned short* __restrict__ wcat) {
  int idx = blockIdx.x * 256 + threadIdx.x;  // 4096*2304
  int n = idx / 2304;
  int k = idx - n * 2304;
  float v = (k < 1280) ? wih[n * 1280 + k] : whh[n * 1024 + (k - 1280)];
  wcat[idx] = f2b(v);
}

// W_att [H,E] -> W_att_T bf16 [E,H]
__global__ __launch_bounds__(256) void conv_wattT(const float* __restrict__ watt,
                                                  unsigned short* __restrict__ wt) {
  int idx = blockIdx.x * 256 + threadIdx.x;  // 1024*1024
  int e = idx >> 10, h = idx & 1023;
  wt[idx] = f2b(watt[h * 1024 + e]);
}

__global__ __launch_bounds__(256) void conv_f2b(const float* __restrict__ s,
                                                unsigned short* __restrict__ d, int n) {
  int idx = blockIdx.x * 256 + threadIdx.x;
  if (idx < n) d[idx] = f2b(s[idx]);
}

// W_qa [A=128, K=1024] -> fp32 [K=1024, 128] for coalesced readout
__global__ __launch_bounds__(256) void conv_wqaT(const float* __restrict__ wqa,
                                                 float* __restrict__ wt) {
  int idx = blockIdx.x * 256 + threadIdx.x;  // 131072
  int k = idx >> 7, j = idx & 127;
  wt[idx] = wqa[j * 1024 + k];
}

// h0 = tanh(pooled @ W_init.T + b_init) -> bf16 into Xcat h-slice
__global__ __launch_bounds__(256) void h0_kernel(const float* __restrict__ pooled,
                                                 const float* __restrict__ winit,
                                                 const float* __restrict__ binit,
                                                 unsigned short* __restrict__ xcat) {
  __shared__ float sp[1024];
  int b = blockIdx.x >> 2;
  int j = (blockIdx.x & 3) * 256 + threadIdx.x;
  for (int i = threadIdx.x; i < 1024; i += 256) sp[i] = pooled[b * 1024 + i];
  __syncthreads();
  float acc = binit[j];
  const float* w = winit + (size_t)j * 1024;
  for (int e = 0; e < 1024; ++e) acc += sp[e] * w[e];
  xcat[(size_t)b * 2304 + 1280 + j] = f2b(tanhf(acc));
}

// zero Xcat[:,0:1280) (x part for step 0) and c state
__global__ __launch_bounds__(256) void init0(unsigned short* __restrict__ xcat,
                                             float* __restrict__ c) {
  int idx = blockIdx.x * 256 + threadIdx.x;
  if (idx < 256 * 1280) {
    int b = idx / 1280;
    int k = idx - b * 1280;
    xcat[(size_t)b * 2304 + k] = 0;
  }
  if (idx < 256 * 1024) c[idx] = 0.f;
}

// ---------------- per-step kernels ------------------------------------------

// previous-action / previous-type embeddings into Xcat (t>=1 only)
__global__ __launch_bounds__(256) void embed_x(const int* __restrict__ action_ids,
                                               const int* __restrict__ type_ids,
                                               const float* __restrict__ prod_emb,
                                               const float* __restrict__ type_emb,
                                               unsigned short* __restrict__ xcat, int t) {
  int b = blockIdx.x;
  int tid = threadIdx.x;
  if (tid < 128) {
    int aid = action_ids[t * 256 + b];
    xcat[(size_t)b * 2304 + tid] = f2b(prod_emb[aid * 128 + tid]);
  } else {
    int tyid = type_ids[t * 256 + b];
    xcat[(size_t)b * 2304 + 1152 + (tid - 128)] = f2b(type_emb[tyid * 128 + (tid - 128)]);
  }
}

// C[m,n] = sum_k A[m,k]*Bt[n,k];  A,Bt bf16 K-contiguous.  Block 256thr = 4 waves
// (2x2), block tile 64x64, wave tile 32x32 via 2x2 16x16x32 MFMA fragments.
// EPI 0: store fp32.  EPI 1: tanh, store fp32 C + bf16 into aux (Xcat att slice).
template <int EPI>
__global__ __launch_bounds__(256) void gemm_bt(const unsigned short* __restrict__ A, int lda,
                                               const unsigned short* __restrict__ B, int ldb,
                                               float* __restrict__ C, int ldc, int K,
                                               unsigned short* __restrict__ aux, int aux_ld,
                                               int aux_off) {
  int lane = threadIdx.x & 63;
  int wid = threadIdx.x >> 6;
  int mw = blockIdx.y * 64 + (wid >> 1) * 32;
  int nw = blockIdx.x * 64 + (wid & 1) * 32;
  int lr = lane & 15;
  int kg = lane >> 4;
  const unsigned short* a0p = A + (size_t)(mw + lr) * lda + kg * 8;
  const unsigned short* a1p = a0p + (size_t)16 * lda;
  const unsigned short* b0p = B + (size_t)(nw + lr) * ldb + kg * 8;
  const unsigned short* b1p = b0p + (size_t)16 * ldb;
  f32x4 acc00 = {0.f, 0.f, 0.f, 0.f};
  f32x4 acc01 = acc00, acc10 = acc00, acc11 = acc00;
  for (int k = 0; k < K; k += 32) {
    s16x8 a0 = *(const s16x8*)(a0p + k);
    s16x8 a1 = *(const s16x8*)(a1p + k);
    s16x8 b0 = *(const s16x8*)(b0p + k);
    s16x8 b1 = *(const s16x8*)(b1p + k);
    acc00 = __builtin_amdgcn_mfma_f32_16x16x32_bf16(a0, b0, acc00, 0, 0, 0);
    acc01 = __builtin_amdgcn_mfma_f32_16x16x32_bf16(a0, b1, acc01, 0, 0, 0);
    acc10 = __builtin_amdgcn_mfma_f32_16x16x32_bf16(a1, b0, acc10, 0, 0, 0);
    acc11 = __builtin_amdgcn_mfma_f32_16x16x32_bf16(a1, b1, acc11, 0, 0, 0);
  }
  int r0 = mw + kg * 4;  // C/D layout: col = lane&15, row = (lane>>4)*4 + r
  int c0 = nw + lr;
#pragma unroll
  for (int fi = 0; fi < 2; ++fi) {
#pragma unroll
    for (int fj = 0; fj < 2; ++fj) {
      f32x4 acc = (fi == 0) ? (fj == 0 ? acc00 : acc01) : (fj == 0 ? acc10 : acc11);
      int rr = r0 + fi * 16;
      int cc = c0 + fj * 16;
#pragma unroll
      for (int r = 0; r < 4; ++r) {
        float v = acc[r];
        if (EPI == 1) {
          v = tanhf(v);
          aux[(size_t)(rr + r) * aux_ld + aux_off + cc] = f2b(v);
        }
        C[(size_t)(rr + r) * ldc + cc] = v;
      }
    }
  }
}

// LSTM cell elementwise: gates order i,f,g,o (PyTorch). Writes h as bf16 into
// Xcat h-slice (next step's gates input) and A2 h-slice (this step's att GEMM).
__global__ __launch_bounds__(256) void lstm_cell(const float* __restrict__ gates,
                                                 const float* __restrict__ b_ih,
                                                 const float* __restrict__ b_hh,
                                                 float* __restrict__ c,
                                                 unsigned short* __restrict__ xcat,
                                                 unsigned short* __restrict__ a2) {
  int idx = blockIdx.x * 256 + threadIdx.x;  // 256*1024
  int b = idx >> 10, j = idx & 1023;
  const float* g = gates + (size_t)b * 4096;
  float gi = g[j] + b_ih[j] + b_hh[j];
  float gf = g[j + 1024] + b_ih[j + 1024] + b_hh[j + 1024];
  float gg = g[j + 2048] + b_ih[j + 2048] + b_hh[j + 2048];
  float go = g[j + 3072] + b_ih[j + 3072] + b_hh[j + 3072];
  float ct = sigm(gf) * c[idx] + sigm(gi) * tanhf(gg);
  float ht = sigm(go) * tanhf(ct);
  c[idx] = ct;
  unsigned short hb = f2b(ht);
  xcat[(size_t)b * 2304 + 1280 + j] = hb;
  a2[(size_t)b * 2048 + j] = hb;
}

// Single-pass online-softmax attention, K == V == src row. One block per b,
// 16 waves x 32 rows; lane owns e-slice [lane*16, lane*16+16).
template <int BF16P>
__global__ __launch_bounds__(1024) void flash_attn(const unsigned short* __restrict__ srcb,
                                                   const float* __restrict__ srcf,
                                                   const float* __restrict__ q,
                                                   unsigned short* __restrict__ a2) {
  __shared__ unsigned short lctx[16][1024];
  __shared__ float lm[16], ldn[16], lsc[16];
  __shared__ float sDinv;
  int b = blockIdx.x;
  int wid = threadIdx.x >> 6, lane = threadIdx.x & 63;
  float qr[16];
  {
    const float4* qp = (const float4*)(q + (size_t)b * 1024 + lane * 16);
#pragma unroll
    for (int i = 0; i < 4; ++i) {
      float4 t = qp[i];
      qr[4 * i] = t.x; qr[4 * i + 1] = t.y; qr[4 * i + 2] = t.z; qr[4 * i + 3] = t.w;
    }
  }
  float m = -3e38f, d = 0.f;
  float ctx[16];
#pragma unroll
  for (int i = 0; i < 16; ++i) ctx[i] = 0.f;
  int s0 = wid * 32;

  if (BF16P) {
    const unsigned short* rb = srcb + (size_t)b * 524288 + lane * 16;
    s16x8 u0 = *(const s16x8*)(rb + (size_t)s0 * 1024);
    s16x8 u1 = *(const s16x8*)(rb + (size_t)s0 * 1024 + 8);
    for (int s = 0; s < 32; ++s) {
      int rn = s0 + s + 1;
      rn = rn > 511 ? 511 : rn;  // safe prefetch clamp
      s16x8 n0 = *(const s16x8*)(rb + (size_t)rn * 1024);
      s16x8 n1 = *(const s16x8*)(rb + (size_t)rn * 1024 + 8);
      float v[16];
#pragma unroll
      for (int i = 0; i < 8; ++i) {
        v[i] = b2f((unsigned short)u0[i]);
        v[8 + i] = b2f((unsigned short)u1[i]);
      }
      float sc = 0.f;
#pragma unroll
      for (int i = 0; i < 16; ++i) sc += v[i] * qr[i];
#pragma unroll
      for (int off = 1; off < 64; off <<= 1) sc += __shfl_xor(sc, off);
      float mn = fmaxf(m, sc);
      float scale = __expf(m - mn);
      float wgt = __expf(sc - mn);
      d = d * scale + wgt;
#pragma unroll
      for (int i = 0; i < 16; ++i) ctx[i] = ctx[i] * scale + wgt * v[i];
      m = mn;
      u0 = n0; u1 = n1;
    }
  } else {
    const float* rb = srcf + (size_t)b * 524288 + lane * 16;
    for (int s = 0; s < 32; ++s) {
      int r = s0 + s;
      float v[16];
#pragma unroll
      for (int i = 0; i < 4; ++i) {
        float4 t = *(const float4*)(rb + (size_t)r * 1024 + 4 * i);
        v[4 * i] = t.x; v[4 * i + 1] = t.y; v[4 * i + 2] = t.z; v[4 * i + 3] = t.w;
      }
      float sc = 0.f;
#pragma unroll
      for (int i = 0; i < 16; ++i) sc += v[i] * qr[i];
#pragma unroll
      for (int off = 1; off < 64; off <<= 1) sc += __shfl_xor(sc, off);
      float mn = fmaxf(m, sc);
      float scale = __expf(m - mn);
      float wgt = __expf(sc - mn);
      d = d * scale + wgt;
#pragma unroll
      for (int i = 0; i < 16; ++i) ctx[i] = ctx[i] * scale + wgt * v[i];
      m = mn;
    }
  }

  // cross-wave combine
#pragma unroll
  for (int i = 0; i < 16; ++i) lctx[wid][lane * 16 + i] = f2b(ctx[i]);
  if (lane == 0) { lm[wid] = m; ldn[wid] = d; }
  __syncthreads();
  if (threadIdx.x == 0) {
    float M = lm[0];
    for (int w2 = 1; w2 < 16; ++w2) M = fmaxf(M, lm[w2]);
    float D = 0.f;
    for (int w2 = 0; w2 < 16; ++w2) {
      float sc = __expf(lm[w2] - M);
      lsc[w2] = sc;
      D += sc * ldn[w2];
    }
    sDinv = 1.f / D;
  }
  __syncthreads();
  int e = threadIdx.x;
  float acc = 0.f;
#pragma unroll
  for (int w2 = 0; w2 < 16; ++w2) acc += lsc[w2] * b2f(lctx[w2][e]);
  a2[(size_t)b * 2048 + 1024 + e] = f2b(acc * sDinv);
}

// q2 = tanh(att @ W_qa.T + b_qa); probs = softmax(q2 @ prod_embed.T + prod_bias)
__global__ __launch_bounds__(128) void readout(const float* __restrict__ att,
                                               const float* __restrict__ wqaT,
                                               const float* __restrict__ b_qa,
                                               const float* __restrict__ prod_emb,
                                               const float* __restrict__ prod_bias,
                                               float* __restrict__ out, int t) {
  __shared__ float s_att[1024], s_q2[128], s_log[97], s_red[2];
  int b = blockIdx.x;
  int tid = threadIdx.x;
  for (int i = tid; i < 1024; i += 128) s_att[i] = att[(size_t)b * 1024 + i];
  __syncthreads();
  float acc = b_qa[tid];
  for (int k = 0; k < 1024; ++k) acc += s_att[k] * wqaT[k * 128 + tid];
  s_q2[tid] = tanhf(acc);
  __syncthreads();
  if (tid < 97) {
    float a = prod_bias[tid];
    const float* pe = prod_emb + tid * 128;
    for (int k = 0; k < 128; ++k) a += s_q2[k] * pe[k];
    s_log[tid] = a;
  }
  __syncthreads();
  if (tid == 0) {
    float M = s_log[0];
    for (int k = 1; k < 97; ++k) M = fmaxf(M, s_log[k]);
    float D = 0.f;
    for (int k = 0; k < 97; ++k) D += __expf(s_log[k] - M);
    s_red[0] = M;
    s_red[1] = D;
  }
  __syncthreads();
  if (tid < 97)
    out[((size_t)t * 256 + b) * 97 + tid] = __expf(s_log[tid] - s_red[0]) / s_red[1];
}

// ---------------------------------------------------------------------------

extern "C" void kernel_launch(void* const* d_in, const int* in_sizes, int n_in,
                              void* d_out, int out_size, void* d_ws, size_t ws_size,
                              hipStream_t stream) {
  const float* src = (const float*)d_in[0];
  const int* action = (const int*)d_in[1];
  const int* type_ids = (const int*)d_in[2];
  const float* W_ih = (const float*)d_in[3];
  const float* b_ih = (const float*)d_in[4];
  const float* W_hh = (const float*)d_in[5];
  const float* b_hh = (const float*)d_in[6];
  const float* W_att = (const float*)d_in[7];
  const float* W_av = (const float*)d_in[8];
  const float* W_qa = (const float*)d_in[9];
  const float* b_qa = (const float*)d_in[10];
  const float* prod_emb = (const float*)d_in[11];
  const float* prod_bias = (const float*)d_in[12];
  const float* type_emb = (const float*)d_in[13];
  const float* W_init = (const float*)d_in[14];
  const float* b_init = (const float*)d_in[15];
  float* out = (float*)d_out;

  const size_t NEED_BIG = 304742400ull;   // with bf16 src copy
  const size_t NEED_SMALL = 36306944ull;  // without
  bool big = ws_size >= NEED_BIG;
  if (!big && ws_size < NEED_SMALL) return;  // cannot run

  char* w = (char*)d_ws;
  size_t o = 0;
  unsigned short* srcb = nullptr;
  if (big) { srcb = (unsigned short*)w; o += 268435456ull; }
  unsigned short* wcat = (unsigned short*)(w + o); o += 18874368ull;
  unsigned short* wattT = (unsigned short*)(w + o); o += 2097152ull;
  unsigned short* wav = (unsigned short*)(w + o); o += 4194304ull;
  float* wqaT = (float*)(w + o); o += 524288ull;
  unsigned short* xcat = (unsigned short*)(w + o); o += 1179648ull;  // [256,2304] bf16
  unsigned short* a2 = (unsigned short*)(w + o); o += 1048576ull;    // [256,2048] bf16
  float* gates = (float*)(w + o); o += 4194304ull;                   // [256,4096]
  float* cbuf = (float*)(w + o); o += 1048576ull;                    // [256,1024]
  float* qbuf = (float*)(w + o); o += 1048576ull;                    // [256,1024]
  float* attf = (float*)(w + o); o += 1048576ull;                    // [256,1024]
  float* pooled = (float*)(w + o); o += 1048576ull;                  // [256,1024]

  // ---- prep (every call; deterministic) ----
  if (big) pool_convert<1><<<1024, 256, 0, stream>>>(src, srcb, pooled);
  else     pool_convert<0><<<1024, 256, 0, stream>>>(src, nullptr, pooled);
  conv_wcat<<<36864, 256, 0, stream>>>(W_ih, W_hh, wcat);
  conv_wattT<<<4096, 256, 0, stream>>>(W_att, wattT);
  conv_f2b<<<8192, 256, 0, stream>>>(W_av, wav, 2097152);
  conv_wqaT<<<512, 256, 0, stream>>>(W_qa, wqaT);
  h0_kernel<<<1024, 256, 0, stream>>>(pooled, W_init, b_init, xcat);
  init0<<<1280, 256, 0, stream>>>(xcat, cbuf);

  // ---- 48 recurrent steps ----
  for (int t = 0; t < 48; ++t) {
    if (t) embed_x<<<256, 256, 0, stream>>>(action, type_ids, prod_emb, type_emb, xcat, t);
    // gates = [x|h] @ [W_ih|W_hh]^T
    gemm_bt<0><<<dim3(64, 4), 256, 0, stream>>>(xcat, 2304, wcat, 2304, gates, 4096, 2304,
                                                nullptr, 0, 0);
    lstm_cell<<<1024, 256, 0, stream>>>(gates, b_ih, b_hh, cbuf, xcat, a2);
    // q = h @ W_att  (query projection)
    gemm_bt<0><<<dim3(16, 4), 256, 0, stream>>>(a2, 2048, wattT, 1024, qbuf, 1024, 1024,
                                                nullptr, 0, 0);
    if (big) flash_attn<1><<<256, 1024, 0, stream>>>(srcb, nullptr, qbuf, a2);
    else     flash_attn<0><<<256, 1024, 0, stream>>>(nullptr, src, qbuf, a2);
    // att = tanh([h|ctx] @ W_av^T) -> fp32 for readout + bf16 into next Xcat
    gemm_bt<1><<<dim3(16, 4), 256, 0, stream>>>(a2, 2048, wav, 2048, attf, 1024, 2048,
                                                xcat, 2304, 128);
    readout<<<256, 128, 0, stream>>>(attf, wqaT, b_qa, prod_emb, prod_bias, out, t);
  }
}